// Round 11
// baseline (54.487 us; speedup 1.0000x reference)
//
#include <hip/hip_runtime.h>
#include <hip/hip_bf16.h>

#define NB 32
#define NP 4096
#define NC 128
#define ND 128
#define TP 64             // points per block (16 per wave)
#define EPSV 1e-16f

typedef __attribute__((ext_vector_type(8))) short short8;
typedef __attribute__((ext_vector_type(4))) short short4v;
typedef __attribute__((ext_vector_type(4))) float f32x4;

__device__ __forceinline__ unsigned short f2bf(float f) {
  __hip_bfloat16 h = __float2bfloat16(f);
  return *reinterpret_cast<unsigned short*>(&h);
}

// Nontemporal f32x4 store: keeps the 201MB output stream from thrashing L2
// (write-allocate) against the phase-2 fragment reads. R11's only change.
__device__ __forceinline__ void nt_store4(f32x4 v, float* p) {
  __builtin_nontemporal_store(v, (f32x4*)p);
}

// LDS byte-offset swizzle for wT: row-major [row][128 bf16], XOR (row&7)<<4.
__device__ __forceinline__ int swz(int row, int kbyte) {
  return (row * 256 + kbyte) ^ ((row & 7) << 4);
}

// Pre-kernel v2 (unchanged from R9): per-record MFMA A-fragment images,
// 32KB/record. Fragment (kk, mi, lane): row d = mi*16 + (lane&15),
// k = kk*32 + (lane>>4)*8 .. +8, bf16x8 (16B). id == (kk*8+mi)*64 + lane.
__global__ void cc_pre(const int* __restrict__ indices,
                       const float* __restrict__ codes,
                       unsigned char* __restrict__ ws) {
  const int b = blockIdx.x >> 3;
  const int chunk = blockIdx.x & 7;
  const int rec = indices[b];
  const float* cb = codes + (size_t)rec * (NC * ND);
  unsigned char* wb = ws + (size_t)b * (NC * ND * 2);
  const int id = chunk * 256 + threadIdx.x;
  const int lane = id & 63;
  const int l16 = lane & 15;
  const int kg = (lane >> 4) & 3;
  const int mi = (id >> 6) & 7;
  const int kk = id >> 9;
  const int d = mi * 16 + l16;
  const int cbase = kk * 32 + kg * 8;
  short8 v;
  #pragma unroll
  for (int j = 0; j < 8; ++j)
    v[j] = (short)f2bf(cb[(size_t)(cbase + j) * ND + d]);
  *(short8*)(wb + ((size_t)id * 16)) = v;
}

// R11 = R9 (best: zero-sync, TP=64, fragment streaming) + nontemporal
// output stores. No other change.
template<bool PRE>
__global__ __launch_bounds__(256, 2) void cc_main(
    const int* __restrict__ indices,
    const float* __restrict__ qp,       // (B,P,3)
    const float* __restrict__ cpos,     // (R,C,3)
    const float* __restrict__ codes,    // (R,C,D)
    const void* __restrict__ dsp,       // dist_scale scalar
    const unsigned char* __restrict__ wsc, // fragment images (v2 layout)
    float* __restrict__ out_qc,         // (B,P,D)
    float* __restrict__ out_sq,         // (B,P,C)
    float* __restrict__ out_wt) {       // (B,P,C)
  __shared__ __align__(16) unsigned char wT[TP * NC * 2];   // 16KB, 4KB/wave

  const int tid = threadIdx.x;
  const int lane = tid & 63;
  const int wv = tid >> 6;
  const int g = lane >> 4;            // point-within-quad (phase 1)
  const int l16 = lane & 15;
  const int b = blockIdx.x >> 6;
  const int p0 = (blockIdx.x & 63) * TP;
  const int rec = indices[b];
  unsigned char* wTw = wT + wv * (16 * 256); // this wave's 16-row section

  const int si = ((const int*)dsp)[0];
  const float sv = (si > 0 && si < 1000) ? (float)si : ((const float*)dsp)[0];

  // ---- per-lane code positions: lane owns codes l16*4..+3 and 64+l16*4..+3
  const float* pb0 = cpos + ((size_t)rec * NC + l16 * 4) * 3;
  const float* pb1 = cpos + ((size_t)rec * NC + 64 + l16 * 4) * 3;
  float px[8], py[8], pz[8];
  #pragma unroll
  for (int j = 0; j < 4; ++j) {
    px[j] = pb0[j * 3 + 0]; py[j] = pb0[j * 3 + 1]; pz[j] = pb0[j * 3 + 2];
    px[j + 4] = pb1[j * 3 + 0]; py[j + 4] = pb1[j * 3 + 1]; pz[j + 4] = pb1[j * 3 + 2];
  }

  // ---- q for this wave's 16 points: p = wv*16 + it*4 + g
  const size_t rowbase = (size_t)b * NP + p0;
  float qx[4], qy[4], qz[4];
  #pragma unroll
  for (int it = 0; it < 4; ++it) {
    const int p = wv * 16 + it * 4 + g;
    const float* q = qp + (rowbase + p) * 3;
    qx[it] = q[0]; qy[it] = q[1]; qz[it] = q[2];
  }

  // ---- A-fragment source + kk=0 prefetch (L2 latency hides under phase 1)
  const unsigned char* fb = wsc + (size_t)b * (NC * ND * 2) + (size_t)lane * 16;
  const float* cb = codes + (size_t)rec * (NC * ND);   // fallback path only
  short8 fA[8], fB[8];
  #pragma unroll
  for (int mi = 0; mi < 8; ++mi) {
    if (PRE) {
      fA[mi] = *(const short8*)(fb + (0 * 8 + mi) * 1024);
    } else {
      const int d = mi * 16 + l16;
      const int cbase0 = g * 8;       // kk=0
      #pragma unroll
      for (int j = 0; j < 8; ++j)
        fA[mi][j] = (short)f2bf(cb[(size_t)(cbase0 + j) * ND + d]);
    }
  }

  // ---- phase 1: wave-local points; lane owns 8 codes (4+4 split).
  const bool s2 = (sv == 2.0f);
  #pragma unroll
  for (int it = 0; it < 4; ++it) {
    const int p = wv * 16 + it * 4 + g;
    float dd[8], wu[8];
    #pragma unroll
    for (int j = 0; j < 8; ++j) {
      const float dx = qx[it] - px[j], dy = qy[it] - py[j], dz = qz[it] - pz[j];
      dd[j] = fmaf(dx, dx, fmaf(dy, dy, dz * dz)) + EPSV;
    }
    if (s2) {
      #pragma unroll
      for (int j = 0; j < 8; ++j) wu[j] = __builtin_amdgcn_rcpf(dd[j]);
    } else {
      #pragma unroll
      for (int j = 0; j < 8; ++j) wu[j] = __powf(dd[j], -0.5f * sv);
    }
    float s = ((wu[0] + wu[1]) + (wu[2] + wu[3])) + ((wu[4] + wu[5]) + (wu[6] + wu[7]));
    s += __shfl_xor(s, 1); s += __shfl_xor(s, 2);
    s += __shfl_xor(s, 4); s += __shfl_xor(s, 8);   // within 16-lane group
    const float inv = __builtin_amdgcn_rcpf(s);

    f32x4 dlo, dhi, wlo, whi;
    #pragma unroll
    for (int j = 0; j < 4; ++j) {
      dlo[j] = dd[j]; dhi[j] = dd[j + 4];
      wlo[j] = wu[j] * inv; whi[j] = wu[j + 4] * inv;
    }
    const size_t rb = (rowbase + p) * (size_t)NC;
    nt_store4(dlo, out_sq + rb + l16 * 4);
    nt_store4(dhi, out_sq + rb + 64 + l16 * 4);
    nt_store4(wlo, out_wt + rb + l16 * 4);
    nt_store4(whi, out_wt + rb + 64 + l16 * 4);

    short4v wbl, wbh;
    #pragma unroll
    for (int j = 0; j < 4; ++j) {
      wbl[j] = (short)f2bf(wlo[j]);
      wbh[j] = (short)f2bf(whi[j]);
    }
    const int r = it * 4 + g;
    *(short4v*)(wTw + swz(r, l16 * 8)) = wbl;        // codes l16*4..+3
    *(short4v*)(wTw + swz(r, 128 + l16 * 8)) = wbh;  // codes 64+l16*4..+3
  }

  // ---- phase 2: NO barrier anywhere. wT is wave-local (lgkmcnt ordering);
  // A-fragments stream from L2, pipelined one k-step ahead.
  const int kg = lane >> 4;
  const int prl = wv * 16 + l16;       // this lane's point (local)
  f32x4 acc[8];
  #pragma unroll
  for (int mi = 0; mi < 8; ++mi) acc[mi] = (f32x4){0.f, 0.f, 0.f, 0.f};

  #define LOADF(dst, kknext)                                                   \
    _Pragma("unroll")                                                          \
    for (int mi = 0; mi < 8; ++mi) {                                           \
      if (PRE) {                                                               \
        dst[mi] = *(const short8*)(fb + ((kknext) * 8 + mi) * 1024);           \
      } else {                                                                 \
        const int d = mi * 16 + l16;                                           \
        const int cb0 = (kknext) * 32 + g * 8;                                 \
        _Pragma("unroll")                                                      \
        for (int j = 0; j < 8; ++j)                                            \
          dst[mi][j] = (short)f2bf(cb[(size_t)(cb0 + j) * ND + d]);            \
      }                                                                        \
    }

  #define COMPUTE(src, kk)                                                     \
    {                                                                          \
      const int kb = ((kk) * 32 + kg * 8) * 2;                                 \
      const short8 b0 = *(const short8*)(wTw + swz(l16, kb));                  \
      _Pragma("unroll")                                                        \
      for (int mi = 0; mi < 8; ++mi)                                           \
        acc[mi] = __builtin_amdgcn_mfma_f32_16x16x32_bf16(src[mi], b0,         \
                                                          acc[mi], 0, 0, 0);   \
    }

  LOADF(fB, 1)
  COMPUTE(fA, 0)
  LOADF(fA, 2)
  COMPUTE(fB, 1)
  LOADF(fB, 3)
  COMPUTE(fA, 2)
  COMPUTE(fB, 3)

  #undef LOADF
  #undef COMPUTE

  // D layout: col(=p-offset) = lane&15, row(=d-offset) = (lane>>4)*4 + reg
  float* o0 = out_qc + (rowbase + prl) * (size_t)ND + kg * 4;
  #pragma unroll
  for (int mi = 0; mi < 8; ++mi)
    nt_store4(acc[mi], o0 + mi * 16);
}

extern "C" void kernel_launch(void* const* d_in, const int* in_sizes, int n_in,
                              void* d_out, int out_size, void* d_ws, size_t ws_size,
                              hipStream_t stream) {
  const int* indices = (const int*)d_in[0];
  const float* qp = (const float*)d_in[1];
  const float* cpos = (const float*)d_in[2];
  const float* codes = (const float*)d_in[3];
  const void* dsp = d_in[4];

  float* out = (float*)d_out;
  float* qc = out;                                   // (B,P,D)
  float* sq = qc + (size_t)NB * NP * ND;             // (B,P,C)
  float* wt = sq + (size_t)NB * NP * NC;             // (B,P,C)

  const size_t ws_need = (size_t)NB * NC * ND * 2;   // 1 MiB
  dim3 grid(NB * (NP / TP));                         // 2048 blocks
  if (ws_size >= ws_need) {
    cc_pre<<<dim3(NB * 8), dim3(256), 0, stream>>>(indices, codes, (unsigned char*)d_ws);
    cc_main<true><<<grid, 256, 0, stream>>>(indices, qp, cpos, codes, dsp,
                                            (const unsigned char*)d_ws, qc, sq, wt);
  } else {
    cc_main<false><<<grid, 256, 0, stream>>>(indices, qp, cpos, codes, dsp,
                                             nullptr, qc, sq, wt);
  }
}

// Round 12
// 39.014 us; speedup vs baseline: 1.3966x; 1.3966x over previous
//
#include <hip/hip_runtime.h>
#include <hip/hip_bf16.h>

#define NB 32
#define NP 4096
#define NC 128
#define ND 128
#define TP 64             // points per block (16 per wave)
#define EPSV 1e-16f

typedef __attribute__((ext_vector_type(8))) short short8;
typedef __attribute__((ext_vector_type(4))) short short4v;
typedef __attribute__((ext_vector_type(4))) float f32x4;

__device__ __forceinline__ unsigned short f2bf(float f) {
  __hip_bfloat16 h = __float2bfloat16(f);
  return *reinterpret_cast<unsigned short*>(&h);
}

// LDS byte-offset swizzle: row-major [row][128 bf16], XOR (row&7)<<4.
// Phase-2 reads (16 lanes x 16 rows at one column-slice) land 2 lanes/bank
// (free, m136); XOR only moves bits 4-6 so aligned 16B accesses stay intact.
__device__ __forceinline__ int swz(int row, int kbyte) {
  return (row * 256 + kbyte) ^ ((row & 7) << 4);
}

// R12: SINGLE-LAUNCH kernel (cc_pre + its graph dependency eliminated).
// Per block: inline-stage codes^T -> bf16 cT in LDS (thread owns one d-row:
// lane-coalesced 4B loads, packed ds_write_b128), then R8's validated
// structure: one pre-phase-1 barrier (no stores in flight), wave-local wT,
// swapped-operand MFMA phase 2.
__global__ __launch_bounds__(256, 2) void cc_all(
    const int* __restrict__ indices,
    const float* __restrict__ qp,       // (B,P,3)
    const float* __restrict__ cpos,     // (R,C,3)
    const float* __restrict__ codes,    // (R,C,D)
    const void* __restrict__ dsp,       // dist_scale scalar
    float* __restrict__ out_qc,         // (B,P,D)
    float* __restrict__ out_sq,         // (B,P,C)
    float* __restrict__ out_wt) {       // (B,P,C)
  __shared__ __align__(16) unsigned char cT[ND * NC * 2];   // 32KB [d][c] swz
  __shared__ __align__(16) unsigned char wT[TP * NC * 2];   // 16KB, 4KB/wave

  const int tid = threadIdx.x;
  const int lane = tid & 63;
  const int wv = tid >> 6;
  const int g = lane >> 4;            // point-within-quad (phase 1)
  const int l16 = lane & 15;
  const int b = blockIdx.x >> 6;
  const int p0 = (blockIdx.x & 63) * TP;
  const int rec = indices[b];
  unsigned char* wTw = wT + wv * (16 * 256); // this wave's 16-row section

  const int si = ((const int*)dsp)[0];
  const float sv = (si > 0 && si < 1000) ? (float)si : ((const float*)dsp)[0];

  // ---- inline cT staging: thread owns row d = tid&127, c-range (tid>>7)*64.
  // Loads: cb[c*128 + d] — consecutive lanes -> consecutive d -> 256B/instr.
  // Writes: 8 x ds_write_b128 (8 bf16 along c within row d, swizzled).
  const float* cb = codes + (size_t)rec * (NC * ND);
  {
    const int d = tid & 127;
    const int c0s = (tid >> 7) * 64;
    const float* cbrow = cb + d;
    #pragma unroll
    for (int o = 0; o < 8; ++o) {
      short8 v;
      #pragma unroll
      for (int j = 0; j < 8; ++j)
        v[j] = (short)f2bf(cbrow[(size_t)(c0s + o * 8 + j) * ND]);
      *(short8*)(cT + swz(d, (c0s + o * 8) * 2)) = v;
    }
  }

  // ---- per-lane code positions: lane owns codes l16*4..+3 and 64+l16*4..+3
  const float* pb0 = cpos + ((size_t)rec * NC + l16 * 4) * 3;
  const float* pb1 = cpos + ((size_t)rec * NC + 64 + l16 * 4) * 3;
  float px[8], py[8], pz[8];
  #pragma unroll
  for (int j = 0; j < 4; ++j) {
    px[j] = pb0[j * 3 + 0]; py[j] = pb0[j * 3 + 1]; pz[j] = pb0[j * 3 + 2];
    px[j + 4] = pb1[j * 3 + 0]; py[j + 4] = pb1[j * 3 + 1]; pz[j + 4] = pb1[j * 3 + 2];
  }

  // ---- q for this wave's 16 points: p = wv*16 + it*4 + g
  const size_t rowbase = (size_t)b * NP + p0;
  float qx[4], qy[4], qz[4];
  #pragma unroll
  for (int it = 0; it < 4; ++it) {
    const int p = wv * 16 + it * 4 + g;
    const float* q = qp + (rowbase + p) * 3;
    qx[it] = q[0]; qy[it] = q[1]; qz[it] = q[2];
  }

  __syncthreads();   // ONLY barrier: drains staging loads/LDS writes + the
                     // q/pos register loads. Zero global stores in flight.

  // ---- phase 1: wave-local points; lane owns 8 codes (4+4 split).
  const bool s2 = (sv == 2.0f);
  #pragma unroll
  for (int it = 0; it < 4; ++it) {
    const int p = wv * 16 + it * 4 + g;
    float dd[8], wu[8];
    #pragma unroll
    for (int j = 0; j < 8; ++j) {
      const float dx = qx[it] - px[j], dy = qy[it] - py[j], dz = qz[it] - pz[j];
      dd[j] = fmaf(dx, dx, fmaf(dy, dy, dz * dz)) + EPSV;
    }
    if (s2) {
      #pragma unroll
      for (int j = 0; j < 8; ++j) wu[j] = __builtin_amdgcn_rcpf(dd[j]);
    } else {
      #pragma unroll
      for (int j = 0; j < 8; ++j) wu[j] = __powf(dd[j], -0.5f * sv);
    }
    float s = ((wu[0] + wu[1]) + (wu[2] + wu[3])) + ((wu[4] + wu[5]) + (wu[6] + wu[7]));
    s += __shfl_xor(s, 1); s += __shfl_xor(s, 2);
    s += __shfl_xor(s, 4); s += __shfl_xor(s, 8);   // within 16-lane group
    const float inv = __builtin_amdgcn_rcpf(s);

    f32x4 dlo, dhi, wlo, whi;
    #pragma unroll
    for (int j = 0; j < 4; ++j) {
      dlo[j] = dd[j]; dhi[j] = dd[j + 4];
      wlo[j] = wu[j] * inv; whi[j] = wu[j + 4] * inv;
    }
    const size_t rb = (rowbase + p) * (size_t)NC;
    *(f32x4*)(out_sq + rb + l16 * 4) = dlo;
    *(f32x4*)(out_sq + rb + 64 + l16 * 4) = dhi;
    *(f32x4*)(out_wt + rb + l16 * 4) = wlo;
    *(f32x4*)(out_wt + rb + 64 + l16 * 4) = whi;

    short4v wbl, wbh;
    #pragma unroll
    for (int j = 0; j < 4; ++j) {
      wbl[j] = (short)f2bf(wlo[j]);
      wbh[j] = (short)f2bf(whi[j]);
    }
    const int r = it * 4 + g;
    *(short4v*)(wTw + swz(r, l16 * 8)) = wbl;        // codes l16*4..+3
    *(short4v*)(wTw + swz(r, 128 + l16 * 8)) = wbh;  // codes 64+l16*4..+3
  }

  // ---- phase 2: no further barrier (wT is wave-local; cT synced above).
  // Phase-1 stores drain underneath the MFMA.
  const int kg = lane >> 4;
  const int prl = wv * 16 + l16;       // this lane's point (local)
  f32x4 acc[8];
  #pragma unroll
  for (int mi = 0; mi < 8; ++mi) acc[mi] = (f32x4){0.f, 0.f, 0.f, 0.f};

  #pragma unroll
  for (int kk = 0; kk < NC; kk += 32) {
    const int kb = (kk + kg * 8) * 2;
    const short8 b0 = *(const short8*)(wTw + swz(l16, kb));
    #pragma unroll
    for (int mi = 0; mi < 8; ++mi) {
      const short8 a8 = *(const short8*)(cT + swz(mi * 16 + l16, kb));
      acc[mi] = __builtin_amdgcn_mfma_f32_16x16x32_bf16(a8, b0, acc[mi], 0, 0, 0);
    }
  }

  // D layout: col(=p-offset) = lane&15, row(=d-offset) = (lane>>4)*4 + reg
  float* o0 = out_qc + (rowbase + prl) * (size_t)ND + kg * 4;
  #pragma unroll
  for (int mi = 0; mi < 8; ++mi)
    *(f32x4*)(o0 + mi * 16) = acc[mi];
}

extern "C" void kernel_launch(void* const* d_in, const int* in_sizes, int n_in,
                              void* d_out, int out_size, void* d_ws, size_t ws_size,
                              hipStream_t stream) {
  const int* indices = (const int*)d_in[0];
  const float* qp = (const float*)d_in[1];
  const float* cpos = (const float*)d_in[2];
  const float* codes = (const float*)d_in[3];
  const void* dsp = d_in[4];

  float* out = (float*)d_out;
  float* qc = out;                                   // (B,P,D)
  float* sq = qc + (size_t)NB * NP * ND;             // (B,P,C)
  float* wt = sq + (size_t)NB * NP * NC;             // (B,P,C)

  dim3 grid(NB * (NP / TP));                         // 2048 blocks, 1 launch
  cc_all<<<grid, 256, 0, stream>>>(indices, qp, cpos, codes, dsp, qc, sq, wt);
}